// Round 4
// baseline (207.434 us; speedup 1.0000x reference)
//
#include <hip/hip_runtime.h>
#include <hip/hip_bf16.h>

// Problem constants (match reference)
#define B_   8
#define NQ_  64     // N_CANDS
#define CTX_ 512    // CTX_LEN
#define DC_  512    // CONTEXT_SIZE
#define DQ_  512    // QUERY_SIZE
#define H_   256    // HIDDEN
#define EPS_ 1e-5f

#define NBLK_ 576   // fused grid: 3 blocks/CU co-resident (<= 3*256 = 768)

using short8  = __attribute__((ext_vector_type(8))) short;  // 8 bf16 (4 VGPRs)
using floatx4 = __attribute__((ext_vector_type(4))) float;  // MFMA acc

// 2 fp32 -> packed bf16x2 via v_cvt_pk_bf16_f32 (single instruction on gfx950)
__device__ __forceinline__ unsigned pk2(float x, float y) {
    union { __hip_bfloat162 h; unsigned u; } c;
    c.h = __float22bfloat162_rn(make_float2(x, y));
    return c.u;
}
// 8 fp32 (two float4) -> 16B packed bf16
__device__ __forceinline__ uint4 cvt8u(float4 a, float4 b) {
    uint4 r;
    r.x = pk2(a.x, a.y); r.y = pk2(a.z, a.w);
    r.z = pk2(b.x, b.y); r.w = pk2(b.z, b.w);
    return r;
}

// LDS is reused across the three phases (max member = 27.6 KB -> 3+ blocks/CU)
union SharedU {
    struct { unsigned short As[2][32][72]; unsigned short Bs[2][64][72]; } g;  // 27.6 KB
    struct { float eqs[8][H_]; float wos[H_]; float ecs[64][68]; float redS[4]; } s; // 26.6 KB
    struct { float ws[CTX_][8]; float pc[3][64][8]; } o;                       // 22.5 KB
};

// Software grid barrier: every block releases its XCD L2, arrives on a
// device-scope counter, spins until all NBLK_ arrived, then acquires
// (invalidates) so cross-XCD writes are visible (guide §6 G16).
__device__ __forceinline__ void grid_barrier(unsigned* cnt, unsigned target) {
    __syncthreads();                       // all block ops done (drains vmcnt)
    if (threadIdx.x == 0) {
        __builtin_amdgcn_fence(__ATOMIC_RELEASE, "agent");   // wb L2
        atomicAdd(cnt, 1u);                                  // device scope
        while (__hip_atomic_load(cnt, __ATOMIC_RELAXED,
                                 __HIP_MEMORY_SCOPE_AGENT) < target)
            __builtin_amdgcn_s_sleep(2);
        __builtin_amdgcn_fence(__ATOMIC_ACQUIRE, "agent");   // inv L2
    }
    __syncthreads();
}

// ---------------------------------------------------------------------------
// Fused kernel: phase1 = gemm_exp (verbatim round-2, measured good),
// phase2 = score (verbatim round-2 staged version, measured good),
// phase3 = out (verbatim round-0 256-thread version, measured good).
// Removes 2 kernel-dispatch drains; eout/Ec stay L2-warm across phases.
// ---------------------------------------------------------------------------
__global__ __launch_bounds__(256, 3) void fused_all(
    const float* __restrict__ ctx, const float* __restrict__ query,
    const float* __restrict__ W_c, const float* __restrict__ b_c,
    const float* __restrict__ W_q, const float* __restrict__ W_o,
    const float* __restrict__ b_o_p, const float* __restrict__ mask,
    const float* __restrict__ context,
    float* __restrict__ Ec, float* __restrict__ Eq,
    float* __restrict__ eout, float* __restrict__ out,
    float* __restrict__ wout, unsigned* __restrict__ cnt)
{
    __shared__ SharedU sh;
    const int bid = blockIdx.x;
    const int t   = threadIdx.x;

    // ======================= Phase 1: gemm_exp (all 576) ===================
    {
        const int rt = bid >> 2;       // 0..143 (128 ctx + 16 query row-tiles)
        const int ct = bid & 3;        // 0..3

        const float* A; const float* W; const float* bias; float* outp; int row0;
        if (rt < 128) { A = ctx;   W = W_c; bias = b_c;     outp = Ec; row0 = rt * 32; }
        else          { A = query; W = W_q; bias = nullptr; outp = Eq; row0 = (rt - 128) * 32; }

        const int col0 = ct * 64;
        const int wave = t >> 6;
        const int lane = t & 63;
        const int m  = lane & 15;
        const int kq = lane >> 4;
        const int mh = wave >> 1;      // M-half: rows mh*16..+16
        const int nh = wave & 1;       // N-half: cols nh*32..+32

        // staging ownership: chunk = 8 fp32 contiguous; r = t>>3, s = t&7
        const int sr = t >> 3, ss = t & 7;
        const float* gA  = A + (size_t)(row0 + sr) * 512 + ss * 8;
        const float* gB0 = W + (size_t)(col0 + sr) * 512 + ss * 8;
        const float* gB1 = W + (size_t)(col0 + 32 + sr) * 512 + ss * 8;
        const int lofs = ss * 8;

        floatx4 acc[2] = {};

        // two register banks (compile-time indexed after full unroll)
        float4 rA0[2], rA1[2], rB00[2], rB01[2], rB10[2], rB11[2];

        // prologue: bank0 <- tile 0, bank1 <- tile 1
        rA0[0]  = *(const float4*)(gA);       rA1[0]  = *(const float4*)(gA + 4);
        rB00[0] = *(const float4*)(gB0);      rB01[0] = *(const float4*)(gB0 + 4);
        rB10[0] = *(const float4*)(gB1);      rB11[0] = *(const float4*)(gB1 + 4);
        rA0[1]  = *(const float4*)(gA + 64);  rA1[1]  = *(const float4*)(gA + 68);
        rB00[1] = *(const float4*)(gB0 + 64); rB01[1] = *(const float4*)(gB0 + 68);
        rB10[1] = *(const float4*)(gB1 + 64); rB11[1] = *(const float4*)(gB1 + 68);

        // write buf0 <- bank0 (tile 0)
        *(uint4*)&sh.g.As[0][sr][lofs]    = cvt8u(rA0[0], rA1[0]);
        *(uint4*)&sh.g.Bs[0][sr][lofs]    = cvt8u(rB00[0], rB01[0]);
        *(uint4*)&sh.g.Bs[0][32+sr][lofs] = cvt8u(rB10[0], rB11[0]);

        #pragma unroll
        for (int s = 0; s < 8; ++s) {
            const int cur = s & 1, nxt = cur ^ 1;
            __syncthreads();           // buf[cur] visible; prev readers of buf[nxt] done

            if (s < 6) {               // loads tile s+2 into bank[cur] (regs now free)
                const int k = (s + 2) * 64;
                rA0[cur]  = *(const float4*)(gA + k);      rA1[cur]  = *(const float4*)(gA + k + 4);
                rB00[cur] = *(const float4*)(gB0 + k);     rB01[cur] = *(const float4*)(gB0 + k + 4);
                rB10[cur] = *(const float4*)(gB1 + k);     rB11[cur] = *(const float4*)(gB1 + k + 4);
            }

            #pragma unroll
            for (int kc = 0; kc < 2; ++kc) {
                short8 af  = *(const short8*)&sh.g.As[cur][mh * 16 + m][kc * 32 + kq * 8];
                short8 b0f = *(const short8*)&sh.g.Bs[cur][nh * 32 +      m][kc * 32 + kq * 8];
                short8 b1f = *(const short8*)&sh.g.Bs[cur][nh * 32 + 16 + m][kc * 32 + kq * 8];
                acc[0] = __builtin_amdgcn_mfma_f32_16x16x32_bf16(af, b0f, acc[0], 0, 0, 0);
                acc[1] = __builtin_amdgcn_mfma_f32_16x16x32_bf16(af, b1f, acc[1], 0, 0, 0);
            }

            if (s < 7) {               // write buf[nxt] <- bank[nxt] (tile s+1)
                *(uint4*)&sh.g.As[nxt][sr][lofs]    = cvt8u(rA0[nxt], rA1[nxt]);
                *(uint4*)&sh.g.Bs[nxt][sr][lofs]    = cvt8u(rB00[nxt], rB01[nxt]);
                *(uint4*)&sh.g.Bs[nxt][32+sr][lofs] = cvt8u(rB10[nxt], rB11[nxt]);
            }
        }

        // Epilogue: D[row=kq*4+i][col=m] per j-tile; write exp(2*(acc+bias))
        #pragma unroll
        for (int j = 0; j < 2; ++j) {
            const int col = col0 + nh * 32 + j * 16 + m;
            const float bb = bias ? bias[col] : 0.f;
            #pragma unroll
            for (int i = 0; i < 4; ++i) {
                const int row = row0 + mh * 16 + kq * 4 + i;
                outp[(size_t)row * H_ + col] = __expf(2.f * (acc[j][i] + bb));
            }
        }
    }

    grid_barrier(cnt, NBLK_);

    // ======================= Phase 2: score (blocks 0..511) ================
    if (bid < 512) {
        const int b     = bid & 7;       // XCD swizzle
        const int ctile = (bid >> 3) & 7;
        const int qg    = bid >> 6;

        const float* eqb = Eq + (size_t)(b * NQ_ + qg * 8) * H_;
        #pragma unroll
        for (int i = 0; i < 8; ++i) ((float*)sh.s.eqs)[t + 256 * i] = eqb[t + 256 * i];
        const float wo_own = W_o[t];
        sh.s.wos[t] = wo_own;
        float S = wo_own;
        #pragma unroll
        for (int k = 1; k < 64; k <<= 1) S += __shfl_xor(S, k);
        if ((t & 63) == 0) sh.s.redS[t >> 6] = S;
        __syncthreads();
        const float base = *b_o_p + sh.s.redS[0] + sh.s.redS[1]
                                  + sh.s.redS[2] + sh.s.redS[3];

        const int cl = t & 63;           // lane's c within tile
        const int qi = t >> 6;           // wave's q-pair
        const int c0 = ctile * 64;
        const float* ec_tile = Ec + (size_t)(b * CTX_ + c0) * H_;
        const int sr = t >> 2, sseg = (t & 3) * 16;       // staging map
        const float* ssrc = ec_tile + (size_t)sr * H_ + sseg;
        const float* eqa = sh.s.eqs[qi * 2];
        const float* eqc = sh.s.eqs[qi * 2 + 1];

        float s0 = 0.f, s1 = 0.f;
        for (int hb = 0; hb < 4; ++hb) {
            float4 v0 = *(const float4*)(ssrc + hb * 64);
            float4 v1 = *(const float4*)(ssrc + hb * 64 + 4);
            float4 v2 = *(const float4*)(ssrc + hb * 64 + 8);
            float4 v3 = *(const float4*)(ssrc + hb * 64 + 12);
            __syncthreads();             // prior chunk's compute done
            float* dst = &sh.s.ecs[sr][sseg];
            *(float4*)(dst)     = v0; *(float4*)(dst + 4)  = v1;
            *(float4*)(dst + 8) = v2; *(float4*)(dst + 12) = v3;
            __syncthreads();
            const int ho = hb * 64;
            #pragma unroll
            for (int h4 = 0; h4 < 16; ++h4) {
                float4 ea = *(const float4*)&sh.s.ecs[cl][h4 * 4];
                float4 qa = *(const float4*)(eqa + ho + h4 * 4);      // broadcast
                float4 qc = *(const float4*)(eqc + ho + h4 * 4);      // broadcast
                float4 w4 = *(const float4*)(sh.s.wos + ho + h4 * 4); // broadcast
                // s0, pair (x,y): one rcp for two h terms
                float ux = fmaf(ea.x, qa.x, 1.f);
                float vx = fmaf(ea.y, qa.y, 1.f);
                s0 = fmaf(fmaf(w4.y, ux, w4.x * vx),
                          __builtin_amdgcn_rcpf(ux * vx), s0);
                // s0, pair (z,w)
                float uz = fmaf(ea.z, qa.z, 1.f);
                float vz = fmaf(ea.w, qa.w, 1.f);
                s0 = fmaf(fmaf(w4.w, uz, w4.z * vz),
                          __builtin_amdgcn_rcpf(uz * vz), s0);
                // s1, pair (x,y)
                float cx = fmaf(ea.x, qc.x, 1.f);
                float dx = fmaf(ea.y, qc.y, 1.f);
                s1 = fmaf(fmaf(w4.y, cx, w4.x * dx),
                          __builtin_amdgcn_rcpf(cx * dx), s1);
                // s1, pair (z,w)
                float cz = fmaf(ea.z, qc.z, 1.f);
                float dz = fmaf(ea.w, qc.w, 1.f);
                s1 = fmaf(fmaf(w4.w, cz, w4.z * dz),
                          __builtin_amdgcn_rcpf(cz * dz), s1);
            }
        }

        const int c = c0 + cl;
        const float mk = mask[b * CTX_ + c];
        const int qa_ = b * NQ_ + qg * 8 + qi * 2;
        eout[(size_t)qa_ * CTX_ + c]       = mk * __expf(base - 2.f * s0);
        eout[(size_t)(qa_ + 1) * CTX_ + c] = mk * __expf(base - 2.f * s1);
    }

    grid_barrier(cnt, 2 * NBLK_);

    // ======================= Phase 3: out (blocks 0..511) ==================
    if (bid < 512) {
        const int b  = bid & 7;
        const int qg = (bid >> 3) & 7;
        const int dq = bid >> 6;           // 0..7: d in [dq*64, +64)

        // Phase 3a: softmax for the 8 q of this qgroup
        {
            const int qi = t >> 5;         // 0..7
            const int cl = t & 31;
            const int q = b * NQ_ + qg * 8 + qi;
            const float* erow = eout + (size_t)q * CTX_;
            float ev[16];
            float part = 0.f;
            #pragma unroll
            for (int k = 0; k < 16; ++k) { ev[k] = erow[cl + 32 * k]; part += ev[k]; }
            part += __shfl_xor(part, 1);  part += __shfl_xor(part, 2);
            part += __shfl_xor(part, 4);  part += __shfl_xor(part, 8);
            part += __shfl_xor(part, 16);
            const float inv = 1.f / (part + EPS_);
            #pragma unroll
            for (int k = 0; k < 16; ++k) {
                const float w = ev[k] * inv;
                sh.o.ws[cl + 32 * k][qi] = w;
                if (dq == 0) wout[(size_t)q * CTX_ + cl + 32 * k] = w;
            }
        }
        __syncthreads();

        // Phase 3b: weighted sum; cq4 = c-quarter, dt = d-lane
        const int cq4 = t >> 6;            // 0..3
        const int dt  = t & 63;
        const int d   = dq * 64 + dt;
        const float* cb = context + ((size_t)(b * CTX_) + cq4 * 128) * DC_ + d;

        float a0=0,a1=0,a2=0,a3=0,a4=0,a5=0,a6=0,a7=0;
        #pragma unroll 4
        for (int c = 0; c < 128; ++c) {
            const float4 wA = *(const float4*)&sh.o.ws[cq4 * 128 + c][0];  // broadcast
            const float4 wB = *(const float4*)&sh.o.ws[cq4 * 128 + c][4];  // broadcast
            const float v = cb[(size_t)c * DC_];
            a0 += wA.x * v; a1 += wA.y * v; a2 += wA.z * v; a3 += wA.w * v;
            a4 += wB.x * v; a5 += wB.y * v; a6 += wB.z * v; a7 += wB.w * v;
        }
        if (cq4) {
            float* p = sh.o.pc[cq4 - 1][dt];
            p[0]=a0; p[1]=a1; p[2]=a2; p[3]=a3; p[4]=a4; p[5]=a5; p[6]=a6; p[7]=a7;
        }
        __syncthreads();
        if (cq4 == 0) {
            float r[8] = {a0,a1,a2,a3,a4,a5,a6,a7};
            #pragma unroll
            for (int j = 0; j < 8; ++j)
                r[j] += sh.o.pc[0][dt][j] + sh.o.pc[1][dt][j] + sh.o.pc[2][dt][j];
            const int qbase = b * NQ_ + qg * 8;
            #pragma unroll
            for (int j = 0; j < 8; ++j)
                out[(size_t)(qbase + j) * DC_ + d] = r[j];
        }
    }
}

extern "C" void kernel_launch(void* const* d_in, const int* in_sizes, int n_in,
                              void* d_out, int out_size, void* d_ws, size_t ws_size,
                              hipStream_t stream) {
    const float* query   = (const float*)d_in[0];  // B,NQ,DQ
    const float* context = (const float*)d_in[1];  // B,CTX,DC
    const float* mask    = (const float*)d_in[2];  // B,CTX
    const float* W_c     = (const float*)d_in[3];  // H,DC
    const float* b_c     = (const float*)d_in[4];  // H
    const float* W_q     = (const float*)d_in[5];  // H,DQ
    const float* W_o     = (const float*)d_in[6];  // H
    const float* b_o     = (const float*)d_in[7];  // scalar

    float* out  = (float*)d_out;                   // B,NQ,DC
    float* wout = out + (size_t)B_ * NQ_ * DC_;    // B,NQ,CTX

    float* Ec   = (float*)d_ws;                        // 4 MB: exp(2*res_c)
    float* Eq   = Ec + (size_t)B_ * CTX_ * H_;         // 512 KB: exp(2*res_q)
    float* eout = Eq + (size_t)B_ * NQ_ * H_;          // 1 MB: mask*exp(logit)
    unsigned* cnt = (unsigned*)((char*)d_ws + (6u << 20));  // barrier counter

    hipMemsetAsync(cnt, 0, 256, stream);           // stream-ordered, capture-safe

    fused_all<<<NBLK_, 256, 0, stream>>>(
        context, query, W_c, b_c, W_q, W_o, b_o, mask, context,
        Ec, Eq, eout, out, wout, cnt);
}

// Round 5
// 107.744 us; speedup vs baseline: 1.9252x; 1.9252x over previous
//
#include <hip/hip_runtime.h>
#include <hip/hip_bf16.h>

// Problem constants (match reference)
#define B_   8
#define NQ_  64     // N_CANDS
#define CTX_ 512    // CTX_LEN
#define DC_  512    // CONTEXT_SIZE
#define DQ_  512    // QUERY_SIZE
#define H_   256    // HIDDEN
#define EPS_ 1e-5f

using short8  = __attribute__((ext_vector_type(8))) short;  // 8 bf16 (4 VGPRs)
using floatx4 = __attribute__((ext_vector_type(4))) float;  // MFMA acc

// 2 fp32 -> packed bf16x2 via v_cvt_pk_bf16_f32 (single instruction on gfx950)
__device__ __forceinline__ unsigned pk2(float x, float y) {
    union { __hip_bfloat162 h; unsigned u; } c;
    c.h = __float22bfloat162_rn(make_float2(x, y));
    return c.u;
}
// 8 fp32 (two float4) -> 16B packed bf16
__device__ __forceinline__ uint4 cvt8u(float4 a, float4 b) {
    uint4 r;
    r.x = pk2(a.x, a.y); r.y = pk2(a.z, a.w);
    r.z = pk2(b.x, b.y); r.w = pk2(b.z, b.w);
    return r;
}

// ---------------------------------------------------------------------------
// Kernel 1: both input GEMMs via bf16 MFMA.  (unchanged — measured good)
// Double-buffered LDS + distance-2 register prefetch, ONE barrier per K-step.
// Epilogue: Ec = exp(2*(acc+bias)), Eq = exp(2*acc).
// ---------------------------------------------------------------------------
__global__ __launch_bounds__(256) void gemm_exp(
    const float* __restrict__ ctx, const float* __restrict__ query,
    const float* __restrict__ W_c, const float* __restrict__ b_c,
    const float* __restrict__ W_q,
    float* __restrict__ Ec, float* __restrict__ Eq)
{
    __shared__ unsigned short As[2][32][72];   // double-buffered A tile
    __shared__ unsigned short Bs[2][64][72];   // double-buffered B tile

    const int rt = blockIdx.x;     // 0..143 (128 ctx + 16 query row-tiles)
    const int ct = blockIdx.y;     // 0..3

    const float* A; const float* W; const float* bias; float* outp; int row0;
    if (rt < 128) { A = ctx;   W = W_c; bias = b_c;     outp = Ec; row0 = rt * 32; }
    else          { A = query; W = W_q; bias = nullptr; outp = Eq; row0 = (rt - 128) * 32; }

    const int col0 = ct * 64;
    const int t    = threadIdx.x;
    const int wave = t >> 6;
    const int lane = t & 63;
    const int m  = lane & 15;
    const int kq = lane >> 4;
    const int mh = wave >> 1;      // M-half: rows mh*16..+16
    const int nh = wave & 1;       // N-half: cols nh*32..+32

    // staging ownership: chunk = 8 fp32 contiguous; r = t>>3, s = t&7
    const int sr = t >> 3, ss = t & 7;
    const float* gA  = A + (size_t)(row0 + sr) * 512 + ss * 8;
    const float* gB0 = W + (size_t)(col0 + sr) * 512 + ss * 8;
    const float* gB1 = W + (size_t)(col0 + 32 + sr) * 512 + ss * 8;
    const int lofs = ss * 8;

    floatx4 acc[2] = {};

    // two register banks (compile-time indexed after full unroll)
    float4 rA0[2], rA1[2], rB00[2], rB01[2], rB10[2], rB11[2];

    // prologue: bank0 <- tile 0, bank1 <- tile 1
    rA0[0]  = *(const float4*)(gA);       rA1[0]  = *(const float4*)(gA + 4);
    rB00[0] = *(const float4*)(gB0);      rB01[0] = *(const float4*)(gB0 + 4);
    rB10[0] = *(const float4*)(gB1);      rB11[0] = *(const float4*)(gB1 + 4);
    rA0[1]  = *(const float4*)(gA + 64);  rA1[1]  = *(const float4*)(gA + 68);
    rB00[1] = *(const float4*)(gB0 + 64); rB01[1] = *(const float4*)(gB0 + 68);
    rB10[1] = *(const float4*)(gB1 + 64); rB11[1] = *(const float4*)(gB1 + 68);

    // write buf0 <- bank0 (tile 0)
    *(uint4*)&As[0][sr][lofs]    = cvt8u(rA0[0], rA1[0]);
    *(uint4*)&Bs[0][sr][lofs]    = cvt8u(rB00[0], rB01[0]);
    *(uint4*)&Bs[0][32+sr][lofs] = cvt8u(rB10[0], rB11[0]);

    #pragma unroll
    for (int s = 0; s < 8; ++s) {
        const int cur = s & 1, nxt = cur ^ 1;
        __syncthreads();           // buf[cur] visible; prev readers of buf[nxt] done

        if (s < 6) {               // loads tile s+2 into bank[cur] (regs now free)
            const int k = (s + 2) * 64;
            rA0[cur]  = *(const float4*)(gA + k);      rA1[cur]  = *(const float4*)(gA + k + 4);
            rB00[cur] = *(const float4*)(gB0 + k);     rB01[cur] = *(const float4*)(gB0 + k + 4);
            rB10[cur] = *(const float4*)(gB1 + k);     rB11[cur] = *(const float4*)(gB1 + k + 4);
        }

        #pragma unroll
        for (int kc = 0; kc < 2; ++kc) {
            short8 af  = *(const short8*)&As[cur][mh * 16 + m][kc * 32 + kq * 8];
            short8 b0f = *(const short8*)&Bs[cur][nh * 32 +      m][kc * 32 + kq * 8];
            short8 b1f = *(const short8*)&Bs[cur][nh * 32 + 16 + m][kc * 32 + kq * 8];
            acc[0] = __builtin_amdgcn_mfma_f32_16x16x32_bf16(af, b0f, acc[0], 0, 0, 0);
            acc[1] = __builtin_amdgcn_mfma_f32_16x16x32_bf16(af, b1f, acc[1], 0, 0, 0);
        }

        if (s < 7) {               // write buf[nxt] <- bank[nxt] (tile s+1,
                                   // loaded one full iteration ago)
            *(uint4*)&As[nxt][sr][lofs]    = cvt8u(rA0[nxt], rA1[nxt]);
            *(uint4*)&Bs[nxt][sr][lofs]    = cvt8u(rB00[nxt], rB01[nxt]);
            *(uint4*)&Bs[nxt][32+sr][lofs] = cvt8u(rB10[nxt], rB11[nxt]);
        }
    }

    // Epilogue: D[row=kq*4+i][col=m] per j-tile; write exp(2*(acc+bias))
    #pragma unroll
    for (int j = 0; j < 2; ++j) {
        const int col = col0 + nh * 32 + j * 16 + m;
        const float bb = bias ? bias[col] : 0.f;
        #pragma unroll
        for (int i = 0; i < 4; ++i) {
            const int row = row0 + mh * 16 + kq * 4 + i;
            outp[(size_t)row * H_ + col] = __expf(2.f * (acc[j][i] + bb));
        }
    }
}

// ---------------------------------------------------------------------------
// Kernel 2: scoring. NEW this round: all wave-uniform operands (Eq rows,
// W_o) moved OFF LDS onto the scalar path — uniform global addresses
// (readfirstlane-forced) compile to s_load through the constant cache.
// Fused-run counters showed wave-uniform b128 LDS reads cost ~9 cy each
// (SQ_LDS_BANK_CONFLICT 8.19M ≈ 917k uniform b128 reads x 9): score was
// LDS-return-bw bound. Per-lane Ec data keeps the measured-good LDS
// staging. h-pairing retained (one rcp per two h terms, HW-verified).
// logit = b_o + Sum(W_o) - 2*sum_h W_o[h]/(Ec[c,h]*Eq[q,h]+1).
// Grid 512 = b(8) x ctile(8: 64c) x qgroup(8: 8q); wave owns 2 q.
// ---------------------------------------------------------------------------
__global__ __launch_bounds__(256) void score_kernel(
    const float* __restrict__ Ec,    // B*CTX*H
    const float* __restrict__ Eqm,   // B*NQ*H
    const float* __restrict__ W_o,   // H
    const float* __restrict__ b_o_p, // scalar
    const float* __restrict__ mask,  // B*CTX
    float* __restrict__ eout)        // B*NQ*CTX
{
    __shared__ float ecs[64][68];    // 64c x 64h chunk, stride-68 pad (17 quads
                                     // per row -> b128 column reads conflict-free)
    __shared__ float redS[4];

    const int blk = blockIdx.x;
    const int b  = blk & 7;          // XCD swizzle
    const int ctile = (blk >> 3) & 7;
    const int qg = blk >> 6;
    const int t  = threadIdx.x;

    // Sum(W_o): per-thread read + butterfly (one-time)
    const float wo_own = W_o[t];
    float S = wo_own;
    #pragma unroll
    for (int k = 1; k < 64; k <<= 1) S += __shfl_xor(S, k);
    if ((t & 63) == 0) redS[t >> 6] = S;

    const int cl = t & 63;           // lane's c within tile
    const int qi = __builtin_amdgcn_readfirstlane(t >> 6);  // wave's q-pair (SGPR)
    const int c0 = ctile * 64;
    const float* ec_tile = Ec + (size_t)(b * CTX_ + c0) * H_;
    const int sr = t >> 2, sseg = (t & 3) * 16;       // staging map
    const float* ssrc = ec_tile + (size_t)sr * H_ + sseg;
    // wave-uniform Eq row pointers -> scalar loads in the loop
    const float* eq0 = Eqm + (size_t)(b * NQ_ + qg * 8 + qi * 2) * H_;
    const float* eq1 = eq0 + H_;

    __syncthreads();                 // redS ready
    const float base = *b_o_p + redS[0] + redS[1] + redS[2] + redS[3];

    float s0 = 0.f, s1 = 0.f;
    for (int hb = 0; hb < 4; ++hb) {
        float4 v0 = *(const float4*)(ssrc + hb * 64);
        float4 v1 = *(const float4*)(ssrc + hb * 64 + 4);
        float4 v2 = *(const float4*)(ssrc + hb * 64 + 8);
        float4 v3 = *(const float4*)(ssrc + hb * 64 + 12);
        __syncthreads();             // prior chunk's compute done
        float* dst = &ecs[sr][sseg];
        *(float4*)(dst)     = v0; *(float4*)(dst + 4)  = v1;
        *(float4*)(dst + 8) = v2; *(float4*)(dst + 12) = v3;
        __syncthreads();
        const int ho = hb * 64;
        #pragma unroll
        for (int h4 = 0; h4 < 16; ++h4) {
            float4 ea = *(const float4*)&ecs[cl][h4 * 4];          // per-lane LDS
            float4 qa = *(const float4*)(eq0 + ho + h4 * 4);       // uniform -> s_load
            float4 qc = *(const float4*)(eq1 + ho + h4 * 4);       // uniform -> s_load
            float4 w4 = *(const float4*)(W_o + ho + h4 * 4);       // uniform -> s_load
            // s0, pair (x,y): one rcp for two h terms
            float ux = fmaf(ea.x, qa.x, 1.f);
            float vx = fmaf(ea.y, qa.y, 1.f);
            s0 = fmaf(fmaf(w4.y, ux, w4.x * vx),
                      __builtin_amdgcn_rcpf(ux * vx), s0);
            // s0, pair (z,w)
            float uz = fmaf(ea.z, qa.z, 1.f);
            float vz = fmaf(ea.w, qa.w, 1.f);
            s0 = fmaf(fmaf(w4.w, uz, w4.z * vz),
                      __builtin_amdgcn_rcpf(uz * vz), s0);
            // s1, pair (x,y)
            float cx = fmaf(ea.x, qc.x, 1.f);
            float dx = fmaf(ea.y, qc.y, 1.f);
            s1 = fmaf(fmaf(w4.y, cx, w4.x * dx),
                      __builtin_amdgcn_rcpf(cx * dx), s1);
            // s1, pair (z,w)
            float cz = fmaf(ea.z, qc.z, 1.f);
            float dz = fmaf(ea.w, qc.w, 1.f);
            s1 = fmaf(fmaf(w4.w, cz, w4.z * dz),
                      __builtin_amdgcn_rcpf(cz * dz), s1);
        }
    }

    const int c = c0 + cl;
    const float mk = mask[b * CTX_ + c];
    const int qa_ = b * NQ_ + qg * 8 + qi * 2;
    eout[(size_t)qa_ * CTX_ + c]       = mk * __expf(base - 2.f * s0);
    eout[(size_t)(qa_ + 1) * CTX_ + c] = mk * __expf(base - 2.f * s1);
}

// ---------------------------------------------------------------------------
// Kernel 3: softmax + weighted context sum. NEW this round: inv[q] factored
// OUT of the accumulation — out[q,d] = inv[q] * sum_c eout[q,c]*ctx[c,d] —
// so the inner loop reads raw eout[q][c] with wave-uniform global addresses
// (-> s_load), eliminating the ws[512][8] LDS buffer and its ~9cy-per-read
// uniform-b128 broadcasts entirely. Reference-exact denom (sum + EPS).
// 512 thr: wave w = c-chunk [w*64,+64), lane = d. Grid 512 = b x qg x dq.
// ---------------------------------------------------------------------------
__global__ __launch_bounds__(512) void out_kernel(
    const float* __restrict__ eout,    // B*NQ*CTX (mask*exp(logit))
    const float* __restrict__ context, // B*CTX*DC
    float* __restrict__ out,           // B*NQ*DC
    float* __restrict__ wout)          // B*NQ*CTX
{
    __shared__ float pc[7][64][8];     // partial sums: 14 KB
    __shared__ float invs[8];

    const int blk = blockIdx.x;
    const int b  = blk & 7;
    const int qg = (blk >> 3) & 7;
    const int dq = blk >> 6;           // 0..7: d in [dq*64, +64)
    const int t  = threadIdx.x;
    const int w    = __builtin_amdgcn_readfirstlane(t >> 6);  // wave id (SGPR)
    const int lane = t & 63;

    // Phase A: wave w computes softmax denom for its q; dq==0 writes wout
    {
        const int q = b * NQ_ + qg * 8 + w;
        const float* erow = eout + (size_t)q * CTX_;
        float ev[8];
        float part = 0.f;
        #pragma unroll
        for (int k = 0; k < 8; ++k) { ev[k] = erow[lane + 64 * k]; part += ev[k]; }
        part += __shfl_xor(part, 1);  part += __shfl_xor(part, 2);
        part += __shfl_xor(part, 4);  part += __shfl_xor(part, 8);
        part += __shfl_xor(part, 16); part += __shfl_xor(part, 32);
        const float inv = 1.f / (part + EPS_);
        if (lane == 0) invs[w] = inv;
        if (dq == 0) {
            #pragma unroll
            for (int k = 0; k < 8; ++k)
                wout[(size_t)q * CTX_ + lane + 64 * k] = ev[k] * inv;
        }
    }

    // Phase B: wave w accumulates its 64-c chunk for all 8 q; lane = d
    const int d = dq * 64 + lane;
    const float* cb    = context + ((size_t)(b * CTX_) + w * 64) * DC_ + d;
    const float* ebase = eout + (size_t)(b * NQ_ + qg * 8) * CTX_ + w * 64;

    float a0=0,a1=0,a2=0,a3=0,a4=0,a5=0,a6=0,a7=0;
    #pragma unroll 4
    for (int cc = 0; cc < 64; cc += 4) {
        // per-lane context values (coalesced VMEM)
        float v0 = cb[(size_t)(cc + 0) * DC_];
        float v1 = cb[(size_t)(cc + 1) * DC_];
        float v2 = cb[(size_t)(cc + 2) * DC_];
        float v3 = cb[(size_t)(cc + 3) * DC_];
        // wave-uniform eout quads (s_load path, L2-hot)
        float4 e0 = *(const float4*)(ebase + 0 * CTX_ + cc);
        float4 e1 = *(const float4*)(ebase + 1 * CTX_ + cc);
        float4 e2 = *(const float4*)(ebase + 2 * CTX_ + cc);
        float4 e3 = *(const float4*)(ebase + 3 * CTX_ + cc);
        float4 e4 = *(const float4*)(ebase + 4 * CTX_ + cc);
        float4 e5 = *(const float4*)(ebase + 5 * CTX_ + cc);
        float4 e6 = *(const float4*)(ebase + 6 * CTX_ + cc);
        float4 e7 = *(const float4*)(ebase + 7 * CTX_ + cc);
        a0 = fmaf(e0.x, v0, fmaf(e0.y, v1, fmaf(e0.z, v2, fmaf(e0.w, v3, a0))));
        a1 = fmaf(e1.x, v0, fmaf(e1.y, v1, fmaf(e1.z, v2, fmaf(e1.w, v3, a1))));
        a2 = fmaf(e2.x, v0, fmaf(e2.y, v1, fmaf(e2.z, v2, fmaf(e2.w, v3, a2))));
        a3 = fmaf(e3.x, v0, fmaf(e3.y, v1, fmaf(e3.z, v2, fmaf(e3.w, v3, a3))));
        a4 = fmaf(e4.x, v0, fmaf(e4.y, v1, fmaf(e4.z, v2, fmaf(e4.w, v3, a4))));
        a5 = fmaf(e5.x, v0, fmaf(e5.y, v1, fmaf(e5.z, v2, fmaf(e5.w, v3, a5))));
        a6 = fmaf(e6.x, v0, fmaf(e6.y, v1, fmaf(e6.z, v2, fmaf(e6.w, v3, a6))));
        a7 = fmaf(e7.x, v0, fmaf(e7.y, v1, fmaf(e7.z, v2, fmaf(e7.w, v3, a7))));
    }

    __syncthreads();                  // invs ready; prior-phase LDS safe
    if (w) {
        float* p = pc[w - 1][lane];
        p[0]=a0; p[1]=a1; p[2]=a2; p[3]=a3; p[4]=a4; p[5]=a5; p[6]=a6; p[7]=a7;
    }
    __syncthreads();
    if (w == 0) {
        float r[8] = {a0,a1,a2,a3,a4,a5,a6,a7};
        #pragma unroll
        for (int pI = 0; pI < 7; ++pI) {
            #pragma unroll
            for (int j = 0; j < 8; ++j) r[j] += pc[pI][lane][j];
        }
        const int qbase = b * NQ_ + qg * 8;
        #pragma unroll
        for (int j = 0; j < 8; ++j)
            out[(size_t)(qbase + j) * DC_ + d] = r[j] * invs[j];
    }
}

extern "C" void kernel_launch(void* const* d_in, const int* in_sizes, int n_in,
                              void* d_out, int out_size, void* d_ws, size_t ws_size,
                              hipStream_t stream) {
    const float* query   = (const float*)d_in[0];  // B,NQ,DQ
    const float* context = (const float*)d_in[1];  // B,CTX,DC
    const float* mask    = (const float*)d_in[2];  // B,CTX
    const float* W_c     = (const float*)d_in[3];  // H,DC
    const float* b_c     = (const float*)d_in[4];  // H
    const float* W_q     = (const float*)d_in[5];  // H,DQ
    const float* W_o     = (const float*)d_in[6];  // H
    const float* b_o     = (const float*)d_in[7];  // scalar

    float* out  = (float*)d_out;                   // B,NQ,DC
    float* wout = out + (size_t)B_ * NQ_ * DC_;    // B,NQ,CTX

    float* Ec   = (float*)d_ws;                        // 4 MB: exp(2*res_c)
    float* Eq   = Ec + (size_t)B_ * CTX_ * H_;         // 512 KB: exp(2*res_q)
    float* eout = Eq + (size_t)B_ * NQ_ * H_;          // 1 MB: mask*exp(logit)

    gemm_exp<<<dim3(144, 4), 256, 0, stream>>>(
        context, query, W_c, b_c, W_q, Ec, Eq);
    score_kernel<<<512, 256, 0, stream>>>(
        Ec, Eq, W_o, b_o, mask, eout);
    out_kernel<<<512, 512, 0, stream>>>(
        eout, context, out, wout);
}

// Round 6
// 106.151 us; speedup vs baseline: 1.9541x; 1.0150x over previous
//
#include <hip/hip_runtime.h>
#include <hip/hip_bf16.h>

// Problem constants (match reference)
#define B_   8
#define NQ_  64     // N_CANDS
#define CTX_ 512    // CTX_LEN
#define DC_  512    // CONTEXT_SIZE
#define DQ_  512    // QUERY_SIZE
#define H_   256    // HIDDEN
#define EPS_ 1e-5f

using short8  = __attribute__((ext_vector_type(8))) short;  // 8 bf16 (4 VGPRs)
using floatx4 = __attribute__((ext_vector_type(4))) float;  // MFMA acc

// 2 fp32 -> packed bf16x2 via v_cvt_pk_bf16_f32 (single instruction on gfx950)
__device__ __forceinline__ unsigned pk2(float x, float y) {
    union { __hip_bfloat162 h; unsigned u; } c;
    c.h = __float22bfloat162_rn(make_float2(x, y));
    return c.u;
}
// 8 fp32 (two float4) -> 16B packed bf16
__device__ __forceinline__ uint4 cvt8u(float4 a, float4 b) {
    uint4 r;
    r.x = pk2(a.x, a.y); r.y = pk2(a.z, a.w);
    r.z = pk2(b.x, b.y); r.w = pk2(b.z, b.w);
    return r;
}

// ---------------------------------------------------------------------------
// Kernel 1: both input GEMMs via bf16 MFMA. NEW this round: K-SPLIT.
// 512 threads = two 256-thread half-blocks; half h accumulates K in
// [h*256, h*256+256) with its OWN double-buffered LDS tiles, running the
// measured-good R2 inner loop for 4 steps instead of 8. Halves merge via
// LDS; half 0 does the exp epilogue. Per-block critical path ~halves;
// occupancy 2 blocks/CU x 8 waves = 4 waves/SIMD (vs 2.25 before).
// Epilogue: Ec = exp(2*(acc+bias)), Eq = exp(2*acc).
// ---------------------------------------------------------------------------
__global__ __launch_bounds__(512) void gemm_exp(
    const float* __restrict__ ctx, const float* __restrict__ query,
    const float* __restrict__ W_c, const float* __restrict__ b_c,
    const float* __restrict__ W_q,
    float* __restrict__ Ec, float* __restrict__ Eq)
{
    __shared__ unsigned short As[2][2][32][72];   // [half][dbuf]: 18 KB
    __shared__ unsigned short Bs[2][2][64][72];   // [half][dbuf]: 36 KB

    const int rt = blockIdx.x;     // 0..143 (128 ctx + 16 query row-tiles)
    const int ct = blockIdx.y;     // 0..3

    const float* A; const float* W; const float* bias; float* outp; int row0;
    if (rt < 128) { A = ctx;   W = W_c; bias = b_c;     outp = Ec; row0 = rt * 32; }
    else          { A = query; W = W_q; bias = nullptr; outp = Eq; row0 = (rt - 128) * 32; }

    const int col0 = ct * 64;
    const int t    = threadIdx.x;
    const int half = t >> 8;       // 0: K[0,256), 1: K[256,512)
    const int th   = t & 255;      // index within half-block
    const int wave = th >> 6;
    const int lane = th & 63;
    const int m  = lane & 15;
    const int kq = lane >> 4;
    const int mh = wave >> 1;      // M-half: rows mh*16..+16
    const int nh = wave & 1;       // N-half: cols nh*32..+32

    // staging ownership within half: chunk = 8 fp32; r = th>>3, s = th&7
    const int sr = th >> 3, ss = th & 7;
    const int koff = half * 256;   // this half's K base (floats)
    const float* gA  = A + (size_t)(row0 + sr) * 512 + koff + ss * 8;
    const float* gB0 = W + (size_t)(col0 + sr) * 512 + koff + ss * 8;
    const float* gB1 = W + (size_t)(col0 + 32 + sr) * 512 + koff + ss * 8;
    const int lofs = ss * 8;

    floatx4 acc[2] = {};

    // two register banks (compile-time indexed after full unroll)
    float4 rA0[2], rA1[2], rB00[2], rB01[2], rB10[2], rB11[2];

    // prologue: bank0 <- subtile 0, bank1 <- subtile 1 (of this half)
    rA0[0]  = *(const float4*)(gA);       rA1[0]  = *(const float4*)(gA + 4);
    rB00[0] = *(const float4*)(gB0);      rB01[0] = *(const float4*)(gB0 + 4);
    rB10[0] = *(const float4*)(gB1);      rB11[0] = *(const float4*)(gB1 + 4);
    rA0[1]  = *(const float4*)(gA + 64);  rA1[1]  = *(const float4*)(gA + 68);
    rB00[1] = *(const float4*)(gB0 + 64); rB01[1] = *(const float4*)(gB0 + 68);
    rB10[1] = *(const float4*)(gB1 + 64); rB11[1] = *(const float4*)(gB1 + 68);

    // write buf0 <- bank0 (subtile 0)
    *(uint4*)&As[half][0][sr][lofs]    = cvt8u(rA0[0], rA1[0]);
    *(uint4*)&Bs[half][0][sr][lofs]    = cvt8u(rB00[0], rB01[0]);
    *(uint4*)&Bs[half][0][32+sr][lofs] = cvt8u(rB10[0], rB11[0]);

    #pragma unroll
    for (int s = 0; s < 4; ++s) {
        const int cur = s & 1, nxt = cur ^ 1;
        __syncthreads();           // buf[cur] visible; prev readers of buf[nxt] done

        if (s < 2) {               // loads subtile s+2 into bank[cur]
            const int k = (s + 2) * 64;
            rA0[cur]  = *(const float4*)(gA + k);      rA1[cur]  = *(const float4*)(gA + k + 4);
            rB00[cur] = *(const float4*)(gB0 + k);     rB01[cur] = *(const float4*)(gB0 + k + 4);
            rB10[cur] = *(const float4*)(gB1 + k);     rB11[cur] = *(const float4*)(gB1 + k + 4);
        }

        #pragma unroll
        for (int kc = 0; kc < 2; ++kc) {
            short8 af  = *(const short8*)&As[half][cur][mh * 16 + m][kc * 32 + kq * 8];
            short8 b0f = *(const short8*)&Bs[half][cur][nh * 32 +      m][kc * 32 + kq * 8];
            short8 b1f = *(const short8*)&Bs[half][cur][nh * 32 + 16 + m][kc * 32 + kq * 8];
            acc[0] = __builtin_amdgcn_mfma_f32_16x16x32_bf16(af, b0f, acc[0], 0, 0, 0);
            acc[1] = __builtin_amdgcn_mfma_f32_16x16x32_bf16(af, b1f, acc[1], 0, 0, 0);
        }

        if (s < 3) {               // write buf[nxt] <- bank[nxt] (subtile s+1)
            *(uint4*)&As[half][nxt][sr][lofs]    = cvt8u(rA0[nxt], rA1[nxt]);
            *(uint4*)&Bs[half][nxt][sr][lofs]    = cvt8u(rB00[nxt], rB01[nxt]);
            *(uint4*)&Bs[half][nxt][32+sr][lofs] = cvt8u(rB10[nxt], rB11[nxt]);
        }
    }

    // Merge halves: half 1 parks its partials in LDS (reuse tile space),
    // half 0 adds and runs the epilogue.
    __syncthreads();               // all MFMA reads of As/Bs done
    float* accbuf = (float*)&As[0][0][0][0];      // 8 KB reuse
    if (half == 1) {
        float* p = accbuf + th * 8;
        *(floatx4*)p       = acc[0];
        *(floatx4*)(p + 4) = acc[1];
    }
    __syncthreads();
    if (half == 0) {
        const float* p = accbuf + th * 8;
        const floatx4 o0 = *(const floatx4*)p;
        const floatx4 o1 = *(const floatx4*)(p + 4);
        acc[0] += o0;
        acc[1] += o1;
        // Epilogue: D[row=kq*4+i][col=m] per j-tile; write exp(2*(acc+bias))
        #pragma unroll
        for (int j = 0; j < 2; ++j) {
            const int col = col0 + nh * 32 + j * 16 + m;
            const float bb = bias ? bias[col] : 0.f;
            #pragma unroll
            for (int i = 0; i < 4; ++i) {
                const int row = row0 + mh * 16 + kq * 4 + i;
                outp[(size_t)row * H_ + col] = __expf(2.f * (acc[j][i] + bb));
            }
        }
    }
}

// ---------------------------------------------------------------------------
// Kernel 2: scoring. REVERTED to the R2-exact version (measured best,
// 105.5us total, twice). LDS-staged Ec chunks + wave-uniform LDS broadcasts
// for Eq/W_o; h-pairing (one rcp per two h terms, HW-verified).
// logit = b_o + Sum(W_o) - 2*sum_h W_o[h]/(Ec[c,h]*Eq[q,h]+1).
// Grid 512 = b(8) x ctile(8: 64c) x qgroup(8: 8q). Lane owns one c; wave
// owns 2 q (q-side LDS reads are wave-uniform broadcasts).
// ---------------------------------------------------------------------------
__global__ __launch_bounds__(256) void score_kernel(
    const float* __restrict__ Ec,    // B*CTX*H
    const float* __restrict__ Eqm,   // B*NQ*H
    const float* __restrict__ W_o,   // H
    const float* __restrict__ b_o_p, // scalar
    const float* __restrict__ mask,  // B*CTX
    float* __restrict__ eout)        // B*NQ*CTX
{
    __shared__ float eqs[8][H_];
    __shared__ float wos[H_];
    __shared__ float ecs[64][68];    // 64c x 64h chunk, stride-68 pad
    __shared__ float redS[4];

    const int blk = blockIdx.x;
    const int b  = blk & 7;          // XCD swizzle
    const int ctile = (blk >> 3) & 7;
    const int qg = blk >> 6;
    const int t  = threadIdx.x;

    const float* eqb = Eqm + (size_t)(b * NQ_ + qg * 8) * H_;
    #pragma unroll
    for (int i = 0; i < 8; ++i) ((float*)eqs)[t + 256 * i] = eqb[t + 256 * i];
    const float wo_own = W_o[t];
    wos[t] = wo_own;
    float S = wo_own;
    #pragma unroll
    for (int k = 1; k < 64; k <<= 1) S += __shfl_xor(S, k);
    if ((t & 63) == 0) redS[t >> 6] = S;
    __syncthreads();
    const float base = *b_o_p + redS[0] + redS[1] + redS[2] + redS[3];

    const int cl = t & 63;           // lane's c within tile
    const int qi = t >> 6;           // wave's q-pair
    const int c0 = ctile * 64;
    const float* ec_tile = Ec + (size_t)(b * CTX_ + c0) * H_;
    const int sr = t >> 2, sseg = (t & 3) * 16;       // staging map
    const float* ssrc = ec_tile + (size_t)sr * H_ + sseg;
    const float* eqa = eqs[qi * 2];
    const float* eqc = eqs[qi * 2 + 1];

    float s0 = 0.f, s1 = 0.f;
    for (int hb = 0; hb < 4; ++hb) {
        float4 v0 = *(const float4*)(ssrc + hb * 64);
        float4 v1 = *(const float4*)(ssrc + hb * 64 + 4);
        float4 v2 = *(const float4*)(ssrc + hb * 64 + 8);
        float4 v3 = *(const float4*)(ssrc + hb * 64 + 12);
        __syncthreads();             // prior chunk's compute done
        float* dst = &ecs[sr][sseg];
        *(float4*)(dst)     = v0; *(float4*)(dst + 4)  = v1;
        *(float4*)(dst + 8) = v2; *(float4*)(dst + 12) = v3;
        __syncthreads();
        const int ho = hb * 64;
        #pragma unroll
        for (int h4 = 0; h4 < 16; ++h4) {
            float4 ea = *(const float4*)&ecs[cl][h4 * 4];
            float4 qa = *(const float4*)(eqa + ho + h4 * 4);   // broadcast
            float4 qc = *(const float4*)(eqc + ho + h4 * 4);   // broadcast
            float4 w4 = *(const float4*)(wos + ho + h4 * 4);   // broadcast
            // s0, pair (x,y): one rcp for two h terms
            float ux = fmaf(ea.x, qa.x, 1.f);
            float vx = fmaf(ea.y, qa.y, 1.f);
            s0 = fmaf(fmaf(w4.y, ux, w4.x * vx),
                      __builtin_amdgcn_rcpf(ux * vx), s0);
            // s0, pair (z,w)
            float uz = fmaf(ea.z, qa.z, 1.f);
            float vz = fmaf(ea.w, qa.w, 1.f);
            s0 = fmaf(fmaf(w4.w, uz, w4.z * vz),
                      __builtin_amdgcn_rcpf(uz * vz), s0);
            // s1, pair (x,y)
            float cx = fmaf(ea.x, qc.x, 1.f);
            float dx = fmaf(ea.y, qc.y, 1.f);
            s1 = fmaf(fmaf(w4.y, cx, w4.x * dx),
                      __builtin_amdgcn_rcpf(cx * dx), s1);
            // s1, pair (z,w)
            float cz = fmaf(ea.z, qc.z, 1.f);
            float dz = fmaf(ea.w, qc.w, 1.f);
            s1 = fmaf(fmaf(w4.w, cz, w4.z * dz),
                      __builtin_amdgcn_rcpf(cz * dz), s1);
        }
    }

    const int c = c0 + cl;
    const float mk = mask[b * CTX_ + c];
    const int qa_ = b * NQ_ + qg * 8 + qi * 2;
    eout[(size_t)qa_ * CTX_ + c]       = mk * __expf(base - 2.f * s0);
    eout[(size_t)(qa_ + 1) * CTX_ + c] = mk * __expf(base - 2.f * s1);
}

// ---------------------------------------------------------------------------
// Kernel 3: softmax (reference-exact: denom = sum + EPS) + weighted context
// sum. REVERTED to R2-exact (measured best). 512-thread blocks; c split
// 8-ways; context loads batched 8-deep. Grid 512 = b(8) x qg(8) x dq(8).
// ---------------------------------------------------------------------------
__global__ __launch_bounds__(512) void out_kernel(
    const float* __restrict__ eout,    // B*NQ*CTX (mask*exp(logit))
    const float* __restrict__ context, // B*CTX*DC
    float* __restrict__ out,           // B*NQ*DC
    float* __restrict__ wout)          // B*NQ*CTX
{
    __shared__ float ws[CTX_][8];      // q-major weights: 16 KB
    __shared__ float pc[7][64][8];     // partial sums: 14 KB

    const int blk = blockIdx.x;
    const int b  = blk & 7;
    const int qg = (blk >> 3) & 7;
    const int dq = blk >> 6;           // 0..7: d in [dq*64, +64)
    const int t  = threadIdx.x;

    // Phase 1: softmax for the 8 q of this qgroup (one q per wave)
    {
        const int qi = t >> 6;         // 0..7
        const int cl = t & 63;
        const int q = b * NQ_ + qg * 8 + qi;
        const float* erow = eout + (size_t)q * CTX_;
        float ev[8];
        float part = 0.f;
        #pragma unroll
        for (int k = 0; k < 8; ++k) { ev[k] = erow[cl + 64 * k]; part += ev[k]; }
        part += __shfl_xor(part, 1);  part += __shfl_xor(part, 2);
        part += __shfl_xor(part, 4);  part += __shfl_xor(part, 8);
        part += __shfl_xor(part, 16); part += __shfl_xor(part, 32);
        const float inv = 1.f / (part + EPS_);
        #pragma unroll
        for (int k = 0; k < 8; ++k) {
            const float w = ev[k] * inv;
            ws[cl + 64 * k][qi] = w;
            if (dq == 0) wout[(size_t)q * CTX_ + cl + 64 * k] = w;
        }
    }
    __syncthreads();

    // Phase 2: weighted sum; cq = c-eighth, dt = d-lane
    const int cq = t >> 6;             // 0..7
    const int dt = t & 63;
    const int d  = dq * 64 + dt;
    const float* cb = context + ((size_t)(b * CTX_) + cq * 64) * DC_ + d;

    float a0=0,a1=0,a2=0,a3=0,a4=0,a5=0,a6=0,a7=0;
    #pragma unroll 2
    for (int cc = 0; cc < 64; cc += 8) {
        float vv[8];
        #pragma unroll
        for (int k = 0; k < 8; ++k) vv[k] = cb[(size_t)(cc + k) * DC_];
        #pragma unroll
        for (int k = 0; k < 8; ++k) {
            const float4 wA = *(const float4*)&ws[cq * 64 + cc + k][0];  // broadcast
            const float4 wB = *(const float4*)&ws[cq * 64 + cc + k][4];  // broadcast
            a0 += wA.x * vv[k]; a1 += wA.y * vv[k]; a2 += wA.z * vv[k]; a3 += wA.w * vv[k];
            a4 += wB.x * vv[k]; a5 += wB.y * vv[k]; a6 += wB.z * vv[k]; a7 += wB.w * vv[k];
        }
    }
    if (cq) {
        float4* p = (float4*)pc[cq - 1][dt];
        p[0] = make_float4(a0, a1, a2, a3);
        p[1] = make_float4(a4, a5, a6, a7);
    }
    __syncthreads();
    if (cq == 0) {
        float r[8] = {a0, a1, a2, a3, a4, a5, a6, a7};
        #pragma unroll
        for (int pI = 0; pI < 7; ++pI) {
            const float4 xA = *(const float4*)&pc[pI][dt][0];
            const float4 xB = *(const float4*)&pc[pI][dt][4];
            r[0] += xA.x; r[1] += xA.y; r[2] += xA.z; r[3] += xA.w;
            r[4] += xB.x; r[5] += xB.y; r[6] += xB.z; r[7] += xB.w;
        }
        const int qbase = b * NQ_ + qg * 8;
        #pragma unroll
        for (int j = 0; j < 8; ++j)
            out[(size_t)(qbase + j) * DC_ + d] = r[j];
    }
}

extern "C" void kernel_launch(void* const* d_in, const int* in_sizes, int n_in,
                              void* d_out, int out_size, void* d_ws, size_t ws_size,
                              hipStream_t stream) {
    const float* query   = (const float*)d_in[0];  // B,NQ,DQ
    const float* context = (const float*)d_in[1];  // B,CTX,DC
    const float* mask    = (const float*)d_in[2];  // B,CTX
    const float* W_c     = (const float*)d_in[3];  // H,DC
    const float* b_c     = (const float*)d_in[4];  // H
    const float* W_q     = (const float*)d_in[5];  // H,DQ
    const float* W_o     = (const float*)d_in[6];  // H
    const float* b_o     = (const float*)d_in[7];  // scalar

    float* out  = (float*)d_out;                   // B,NQ,DC
    float* wout = out + (size_t)B_ * NQ_ * DC_;    // B,NQ,CTX

    float* Ec   = (float*)d_ws;                        // 4 MB: exp(2*res_c)
    float* Eq   = Ec + (size_t)B_ * CTX_ * H_;         // 512 KB: exp(2*res_q)
    float* eout = Eq + (size_t)B_ * NQ_ * H_;          // 1 MB: mask*exp(logit)

    gemm_exp<<<dim3(144, 4), 512, 0, stream>>>(
        context, query, W_c, b_c, W_q, Ec, Eq);
    score_kernel<<<512, 256, 0, stream>>>(
        Ec, Eq, W_o, b_o, mask, eout);
    out_kernel<<<512, 512, 0, stream>>>(
        eout, context, out, wout);
}